// Round 10
// baseline (1427.156 us; speedup 1.0000x reference)
//
#include <hip/hip_runtime.h>
#include <hip/hip_bf16.h>

#define VOCAB 50257
#define EMBED 128
#define BATCH 4096
#define CTX   8

#define BM 128
#define NXT 786            // 64-col strips
#define VPAD 50304
#define LDSP 136

typedef __attribute__((ext_vector_type(8))) short bf16x8;
typedef __attribute__((ext_vector_type(4))) float f32x4;
typedef float f32x4u __attribute__((ext_vector_type(4), aligned(4)));

static __device__ __forceinline__ ushort f2bf(float f) {
  __hip_bfloat16 h = __float2bfloat16(f);
  return *reinterpret_cast<ushort*>(&h);
}

// ---------------- Kernel 1: embedding bag -> bf16 word_emb ----------------
__global__ __launch_bounds__(256) void embed_bag_kernel(
    const int* __restrict__ idx, const float* __restrict__ Wp,
    __hip_bfloat16* __restrict__ emb) {
  int wave = threadIdx.x >> 6;
  int lane = threadIdx.x & 63;
  int row  = blockIdx.x * 4 + wave;
  const int* ri = idx + row * CTX;
  int e0 = lane * 2;
  float s0 = 0.f, s1 = 0.f;
#pragma unroll
  for (int c = 0; c < CTX; ++c) {
    int w = ri[c];
    float2 wv = *reinterpret_cast<const float2*>(Wp + (size_t)w * EMBED + e0);
    s0 += wv.x; s1 += wv.y;
  }
  __hip_bfloat162 pv;
  pv.x = __float2bfloat16(s0);
  pv.y = __float2bfloat16(s1);
  *reinterpret_cast<__hip_bfloat162*>(emb + (size_t)row * EMBED + e0) = pv;
}

// ------- Kernel 1b: W_pred [128][50257]f32 -> Btf fragment-ordered bf16 -------
// Btf[strip][instr=kq*4+n][lane][8]: lane reads exactly its MFMA B-fragment.
__global__ __launch_bounds__(256) void transpose_b_kernel(
    const float* __restrict__ Bm, ushort* __restrict__ Btf) {
  __shared__ ushort Bs[64 * LDSP];
  int x = blockIdx.x;
  int cbase = x * 64;
  int tid = threadIdx.x;
  bool edge = (cbase + 64 > VOCAB);
#pragma unroll
  for (int i = 0; i < 8; ++i) {
    int c  = tid + i * 256;
    int e  = c >> 4;
    int v4 = (c & 15) << 2;
    int col = cbase + v4;
    float4 b;
    if (!edge) {
      b = *reinterpret_cast<const float4*>(Bm + (size_t)e * VOCAB + col);
    } else {
      b.x = (col + 0 < VOCAB) ? Bm[(size_t)e * VOCAB + col + 0] : 0.f;
      b.y = (col + 1 < VOCAB) ? Bm[(size_t)e * VOCAB + col + 1] : 0.f;
      b.z = (col + 2 < VOCAB) ? Bm[(size_t)e * VOCAB + col + 2] : 0.f;
      b.w = (col + 3 < VOCAB) ? Bm[(size_t)e * VOCAB + col + 3] : 0.f;
    }
    Bs[(v4 + 0) * LDSP + e] = f2bf(b.x);
    Bs[(v4 + 1) * LDSP + e] = f2bf(b.y);
    Bs[(v4 + 2) * LDSP + e] = f2bf(b.z);
    Bs[(v4 + 3) * LDSP + e] = f2bf(b.w);
  }
  __syncthreads();
  int lane = tid & 63, wv = tid >> 6;
  int lr = lane & 15, lg = lane >> 4;
#pragma unroll
  for (int p = 0; p < 4; ++p) {
    int instr = p * 4 + wv;
    int kq = instr >> 2, n = instr & 3;
    int v  = n * 16 + lr;
    int e0 = kq * 32 + lg * 8;
    uint4 val = *reinterpret_cast<const uint4*>(&Bs[v * LDSP + e0]);
    *reinterpret_cast<uint4*>(Btf + (size_t)x * 8192 + instr * 512 + lane * 8) = val;
  }
}

// ------ Kernel 2: stream-shaped GEMM (fill-like write profile) ------
// 128 blocks; block rb owns rows rb*32..rb*32+31. 4 waves = 2 row-groups x
// 2 col-halves. Each wave sweeps its 393-strip half SEQUENTIALLY: per strip,
// 16 rows x 256B contiguous (4 n-steps: 4 B-frag loads, 4 MFMA, 1 dwordx4
// store). Chip-wide: 8192 monotone ~100KB write fronts (= fill's stream
// profile) instead of ~100K dribbling row-streams; no cross-wave partial-line
// sharing except 2 edges/row. All blocks sweep the same strip trajectory ->
// the hot Btf slice stays L2/L3-resident.
__global__ __launch_bounds__(256) void gemm9_kernel(
    const ushort* __restrict__ A,       // emb bf16 [4096][128]
    const ushort* __restrict__ Btf,     // [786][16][64][8] bf16 frag-ordered
    float* __restrict__ C) {
  int rb   = blockIdx.x;                // 0..127
  int tid  = threadIdx.x;
  int lane = tid & 63;
  int wv   = tid >> 6;
  int lr   = lane & 15;
  int lg   = lane >> 4;
  int rg   = wv >> 1;                   // row group 0/1
  int h    = wv & 1;                    // col half 0/1

  int R0 = rb * 32 + rg * 16;
  const ushort* Ag = A + (size_t)R0 * EMBED;
  bf16x8 af[4];
#pragma unroll
  for (int kq = 0; kq < 4; ++kq)
    af[kq] = *reinterpret_cast<const bf16x8*>(
        Ag + lr * EMBED + kq * 32 + lg * 8);

  float* Crow = C + (size_t)(R0 + lr) * VOCAB;

  int s0 = h * 393;
  int s1 = s0 + 393;
  for (int s = s0; s < s1; ++s) {
    const ushort* Bg = Btf + (size_t)s * 8192 + lane * 8;
    int colb = s * 64 + lg * 4;
    if (s != NXT - 1) {
#pragma unroll
      for (int n = 0; n < 4; ++n) {
        bf16x8 b[4];
#pragma unroll
        for (int kq = 0; kq < 4; ++kq)
          b[kq] = *reinterpret_cast<const bf16x8*>(Bg + (kq * 4 + n) * 512);
        f32x4 acc = {0.f, 0.f, 0.f, 0.f};
#pragma unroll
        for (int kq = 0; kq < 4; ++kq)
          acc = __builtin_amdgcn_mfma_f32_16x16x32_bf16(b[kq], af[kq], acc, 0, 0, 0);
        *reinterpret_cast<f32x4u*>(Crow + colb + n * 16) =
            __builtin_bit_cast(f32x4u, acc);
      }
    } else {
      // strip 785: cols 50240..50256 valid (17). n=0 full; n=1 only col 50256.
#pragma unroll
      for (int n = 0; n < 2; ++n) {
        bf16x8 b[4];
#pragma unroll
        for (int kq = 0; kq < 4; ++kq)
          b[kq] = *reinterpret_cast<const bf16x8*>(Bg + (kq * 4 + n) * 512);
        f32x4 acc = {0.f, 0.f, 0.f, 0.f};
#pragma unroll
        for (int kq = 0; kq < 4; ++kq)
          acc = __builtin_amdgcn_mfma_f32_16x16x32_bf16(b[kq], af[kq], acc, 0, 0, 0);
        int col = colb + n * 16;
        if (n == 0) {
          *reinterpret_cast<f32x4u*>(Crow + col) = __builtin_bit_cast(f32x4u, acc);
        } else if (lg == 0) {
          Crow[col] = acc[0];               // col 50256
        }
      }
    }
  }
}

// ---------------- Fallback GEMM (R2 style) if ws too small ----------------
#define FLDSP 132
__global__ __launch_bounds__(256, 4) void gemm_kernel(
    const __hip_bfloat16* __restrict__ A,
    const float* __restrict__ Bm,
    float* __restrict__ C) {
  __shared__ char BsRaw[64 * FLDSP * 2];
  int bid = blockIdx.x;
  int k8  = bid & 7;
  int j   = bid >> 3;
  int t   = j >> 5;
  int y   = j & 31;
  int x   = k8 + t * 8;
  if (x >= NXT) return;

  int tid  = threadIdx.x;
  int lane = tid & 63;
  int wv   = tid >> 6;
  int lr   = lane & 15;
  int lg   = lane >> 4;
  int r0   = wv * 32;

  const ushort* Ag = reinterpret_cast<const ushort*>(A) + (size_t)(y * BM) * EMBED;
  uint4 a_raw[2][4];
#pragma unroll
  for (int m = 0; m < 2; ++m)
#pragma unroll
    for (int kq = 0; kq < 4; ++kq)
      a_raw[m][kq] = *reinterpret_cast<const uint4*>(
          Ag + (r0 + m * 16 + lr) * EMBED + kq * 32 + lg * 8);

  int cbase = x * 64;
  bool edge = (x == NXT - 1);
  float4 bb[8];
#pragma unroll
  for (int i = 0; i < 8; ++i) {
    int c  = tid + i * 256;
    int e  = c >> 4;
    int v4 = (c & 15) << 2;
    int col = cbase + v4;
    if (!edge) {
      bb[i] = *reinterpret_cast<const float4*>(Bm + (size_t)e * VOCAB + col);
    } else {
      bb[i].x = (col + 0 < VOCAB) ? Bm[(size_t)e * VOCAB + col + 0] : 0.f;
      bb[i].y = (col + 1 < VOCAB) ? Bm[(size_t)e * VOCAB + col + 1] : 0.f;
      bb[i].z = (col + 2 < VOCAB) ? Bm[(size_t)e * VOCAB + col + 2] : 0.f;
      bb[i].w = (col + 3 < VOCAB) ? Bm[(size_t)e * VOCAB + col + 3] : 0.f;
    }
  }
#pragma unroll
  for (int i = 0; i < 8; ++i) {
    int c  = tid + i * 256;
    int e  = c >> 4;
    int v4 = (c & 15) << 2;
    float vals[4] = {bb[i].x, bb[i].y, bb[i].z, bb[i].w};
#pragma unroll
    for (int jj = 0; jj < 4; ++jj) {
      int v   = v4 + jj;
      int off = v * (FLDSP * 2) + ((e * 2) ^ ((v & 28) << 2));
      *reinterpret_cast<ushort*>(BsRaw + off) = f2bf(vals[jj]);
    }
  }
  __syncthreads();

  f32x4 acc[2][4] = {};
#pragma unroll
  for (int kq = 0; kq < 4; ++kq) {
    int ebyte = (kq * 32 + lg * 8) * 2;
    bf16x8 bfr[4];
#pragma unroll
    for (int n = 0; n < 4; ++n) {
      int v   = n * 16 + lr;
      int off = v * (FLDSP * 2) + (ebyte ^ ((v & 28) << 2));
      bfr[n] = *reinterpret_cast<const bf16x8*>(BsRaw + off);
    }
#pragma unroll
    for (int m = 0; m < 2; ++m) {
      bf16x8 af = __builtin_bit_cast(bf16x8, a_raw[m][kq]);
#pragma unroll
      for (int n = 0; n < 4; ++n)
        acc[m][n] = __builtin_amdgcn_mfma_f32_16x16x32_bf16(af, bfr[n], acc[m][n], 0, 0, 0);
    }
  }

  size_t crow0 = (size_t)y * BM + r0;
#pragma unroll
  for (int m = 0; m < 2; ++m) {
#pragma unroll
    for (int n = 0; n < 4; ++n) {
      int colc = cbase + n * 16 + lr;
      if (colc < VOCAB) {
        float* cp = C + (crow0 + m * 16 + lg * 4) * (size_t)VOCAB + colc;
#pragma unroll
        for (int q = 0; q < 4; ++q)
          cp[(size_t)q * VOCAB] = acc[m][n][q];
      }
    }
  }
}

extern "C" void kernel_launch(void* const* d_in, const int* in_sizes, int n_in,
                              void* d_out, int out_size, void* d_ws, size_t ws_size,
                              hipStream_t stream) {
  const int*   idx    = (const int*)d_in[0];
  const float* W_proj = (const float*)d_in[1];
  const float* W_pred = (const float*)d_in[2];
  float*       out    = (float*)d_out;

  __hip_bfloat16* emb = (__hip_bfloat16*)d_ws;                 // [0, 1MB)
  ushort* Btf = (ushort*)((char*)d_ws + (size_t)1048576);      // [1MB, ~13.9MB)
  const size_t needed = (size_t)1048576 + (size_t)VPAD * EMBED * 2;

  embed_bag_kernel<<<BATCH / 4, 256, 0, stream>>>(idx, W_proj, emb);

  if (ws_size >= needed) {
    transpose_b_kernel<<<NXT, 256, 0, stream>>>(W_pred, Btf);
    gemm9_kernel<<<128, 256, 0, stream>>>((const ushort*)emb, Btf, out);
  } else {
    int strips = (NXT + 7) / 8;
    int grid = 8 * strips * 32;
    gemm_kernel<<<grid, 256, 0, stream>>>(emb, W_pred, out);
  }
}

// Round 11
// 490.316 us; speedup vs baseline: 2.9107x; 2.9107x over previous
//
#include <hip/hip_runtime.h>
#include <hip/hip_bf16.h>

#define VOCAB 50257
#define EMBED 128
#define BATCH 4096
#define CTX   8

#define BM 128
#define NXT 786            // 64-col strips
#define VPAD 50304
#define LDSP 136

typedef __attribute__((ext_vector_type(8))) short bf16x8;
typedef __attribute__((ext_vector_type(4))) float f32x4;
typedef float f32x4u __attribute__((ext_vector_type(4), aligned(4)));

static __device__ __forceinline__ ushort f2bf(float f) {
  __hip_bfloat16 h = __float2bfloat16(f);
  return *reinterpret_cast<ushort*>(&h);
}

// ---------------- Kernel 1: embedding bag -> bf16 word_emb ----------------
__global__ __launch_bounds__(256) void embed_bag_kernel(
    const int* __restrict__ idx, const float* __restrict__ Wp,
    __hip_bfloat16* __restrict__ emb) {
  int wave = threadIdx.x >> 6;
  int lane = threadIdx.x & 63;
  int row  = blockIdx.x * 4 + wave;
  const int* ri = idx + row * CTX;
  int e0 = lane * 2;
  float s0 = 0.f, s1 = 0.f;
#pragma unroll
  for (int c = 0; c < CTX; ++c) {
    int w = ri[c];
    float2 wv = *reinterpret_cast<const float2*>(Wp + (size_t)w * EMBED + e0);
    s0 += wv.x; s1 += wv.y;
  }
  __hip_bfloat162 pv;
  pv.x = __float2bfloat16(s0);
  pv.y = __float2bfloat16(s1);
  *reinterpret_cast<__hip_bfloat162*>(emb + (size_t)row * EMBED + e0) = pv;
}

// ------- Kernel 1b: W_pred [128][50257]f32 -> Btf fragment-ordered bf16 -------
// Btf[strip][instr=kq*4+n][lane][8]: lane reads exactly its MFMA B-fragment.
__global__ __launch_bounds__(256) void transpose_b_kernel(
    const float* __restrict__ Bm, ushort* __restrict__ Btf) {
  __shared__ ushort Bs[64 * LDSP];
  int x = blockIdx.x;
  int cbase = x * 64;
  int tid = threadIdx.x;
  bool edge = (cbase + 64 > VOCAB);
#pragma unroll
  for (int i = 0; i < 8; ++i) {
    int c  = tid + i * 256;
    int e  = c >> 4;
    int v4 = (c & 15) << 2;
    int col = cbase + v4;
    float4 b;
    if (!edge) {
      b = *reinterpret_cast<const float4*>(Bm + (size_t)e * VOCAB + col);
    } else {
      b.x = (col + 0 < VOCAB) ? Bm[(size_t)e * VOCAB + col + 0] : 0.f;
      b.y = (col + 1 < VOCAB) ? Bm[(size_t)e * VOCAB + col + 1] : 0.f;
      b.z = (col + 2 < VOCAB) ? Bm[(size_t)e * VOCAB + col + 2] : 0.f;
      b.w = (col + 3 < VOCAB) ? Bm[(size_t)e * VOCAB + col + 3] : 0.f;
    }
    Bs[(v4 + 0) * LDSP + e] = f2bf(b.x);
    Bs[(v4 + 1) * LDSP + e] = f2bf(b.y);
    Bs[(v4 + 2) * LDSP + e] = f2bf(b.z);
    Bs[(v4 + 3) * LDSP + e] = f2bf(b.w);
  }
  __syncthreads();
  int lane = tid & 63, wv = tid >> 6;
  int lr = lane & 15, lg = lane >> 4;
#pragma unroll
  for (int p = 0; p < 4; ++p) {
    int instr = p * 4 + wv;
    int kq = instr >> 2, n = instr & 3;
    int v  = n * 16 + lr;
    int e0 = kq * 32 + lg * 8;
    uint4 val = *reinterpret_cast<const uint4*>(&Bs[v * LDSP + e0]);
    *reinterpret_cast<uint4*>(Btf + (size_t)x * 8192 + instr * 512 + lane * 8) = val;
  }
}

// ------ Kernel 2: fill-shaped stores via per-wave LDS C-tile ------
// 512 blocks (2/CU, 8 waves/CU). Block = (64-row band) x (col section).
// Wave owns 16 rows, sweeps its ~25 groups (256 cols each) monotonically.
// Per group: 16 n-steps {4 B-frag loads, 4 MFMA (swapped), 1 ds_write_b128
// into per-wave LDS tile (stride-68, conflict-free)}, then 16 ds_read_b128 +
// 16 back-to-back 1KB SINGLE-ROW contiguous stores (= fill's instr shape).
// No __syncthreads anywhere; amp=1.0 monotone row runs of ~25KB.
__global__ __launch_bounds__(256, 2) void gemm10_kernel(
    const ushort* __restrict__ A,       // emb bf16 [4096][128]
    const ushort* __restrict__ Btf,     // [786][16][64][8] bf16 frag-ordered
    float* __restrict__ C) {
  __shared__ float Cs[4][64 * 68];      // 69632 B, per-wave 17408 B

  int bid  = blockIdx.x;                // 0..511
  int band = bid >> 3;                  // 0..63
  int sec  = bid & 7;                   // 0..7
  int tid  = threadIdx.x;
  int lane = tid & 63;
  int wv   = tid >> 6;
  int lr   = lane & 15;
  int lg   = lane >> 4;
  int R0   = band * 64 + wv * 16;

  const ushort* Ag = A + (size_t)R0 * EMBED;
  bf16x8 af[4];
#pragma unroll
  for (int kq = 0; kq < 4; ++kq)
    af[kq] = *reinterpret_cast<const bf16x8*>(
        Ag + lr * EMBED + kq * 32 + lg * 8);

  float* Csw = &Cs[wv][0];
  int wbase = lane * 68;                // ds_write base (f32 units)
  int rbas  = (lane & 3) * 16;          // read-back source-lane row block
  int nofs  = (lane >> 2) * 4;          // read-back n offset (f32)

  int g0 = sec * 25;
  int g1 = (sec < 7) ? g0 + 25 : 197;   // sec7: groups 175..196 (incl tail)

  for (int g = g0; g < g1; ++g) {
    const ushort* Bg0 = Btf + (size_t)(g * 4) * 8192 + lane * 8;
    if (g != 196) {
      // ---- compute 16 n-steps -> per-wave LDS ----
#pragma unroll
      for (int ni = 0; ni < 16; ++ni) {
        const ushort* Bp = Bg0 + (size_t)(ni >> 2) * 8192;
        int n = ni & 3;
        bf16x8 b[4];
#pragma unroll
        for (int kq = 0; kq < 4; ++kq)
          b[kq] = *reinterpret_cast<const bf16x8*>(Bp + (kq * 4 + n) * 512);
        f32x4 acc = {0.f, 0.f, 0.f, 0.f};
#pragma unroll
        for (int kq = 0; kq < 4; ++kq)
          acc = __builtin_amdgcn_mfma_f32_16x16x32_bf16(b[kq], af[kq], acc, 0, 0, 0);
        *reinterpret_cast<f32x4*>(&Csw[wbase + ni * 4]) = acc;
      }
      // ---- read back row-major, 16 x 1KB single-row stores ----
      f32x4 v[16];
#pragma unroll
      for (int r = 0; r < 16; ++r)
        v[r] = *reinterpret_cast<const f32x4*>(&Csw[(rbas + r) * 68 + nofs]);
      int colbase = g * 256 + lane * 4;
#pragma unroll
      for (int r = 0; r < 16; ++r)
        *reinterpret_cast<f32x4u*>(C + (size_t)(R0 + r) * VOCAB + colbase) =
            __builtin_bit_cast(f32x4u, v[r]);
    } else {
      // ---- tail group: strips 784,785 -> cols 50176..50256 (81 valid) ----
#pragma unroll
      for (int ni = 0; ni < 8; ++ni) {
        const ushort* Bp = Bg0 + (size_t)(ni >> 2) * 8192;
        int n = ni & 3;
        bf16x8 b[4];
#pragma unroll
        for (int kq = 0; kq < 4; ++kq)
          b[kq] = *reinterpret_cast<const bf16x8*>(Bp + (kq * 4 + n) * 512);
        f32x4 acc = {0.f, 0.f, 0.f, 0.f};
#pragma unroll
        for (int kq = 0; kq < 4; ++kq)
          acc = __builtin_amdgcn_mfma_f32_16x16x32_bf16(b[kq], af[kq], acc, 0, 0, 0);
        *reinterpret_cast<f32x4*>(&Csw[wbase + ni * 4]) = acc;
      }
      int colbase = 196 * 256 + lane * 4;   // 50176 + 4*lane
#pragma unroll
      for (int r = 0; r < 16; ++r) {
        if (lane < 21) {
          f32x4 v = *reinterpret_cast<const f32x4*>(&Csw[(rbas + r) * 68 + nofs]);
          float* cp = C + (size_t)(R0 + r) * VOCAB + colbase;
          if (lane < 20) {
            *reinterpret_cast<f32x4u*>(cp) = __builtin_bit_cast(f32x4u, v);
          } else {
            cp[0] = v[0];                   // col 50256
          }
        }
      }
    }
  }
}

// ---------------- Fallback GEMM (R2 style) if ws too small ----------------
#define FLDSP 132
__global__ __launch_bounds__(256, 4) void gemm_kernel(
    const __hip_bfloat16* __restrict__ A,
    const float* __restrict__ Bm,
    float* __restrict__ C) {
  __shared__ char BsRaw[64 * FLDSP * 2];
  int bid = blockIdx.x;
  int k8  = bid & 7;
  int j   = bid >> 3;
  int t   = j >> 5;
  int y   = j & 31;
  int x   = k8 + t * 8;
  if (x >= NXT) return;

  int tid  = threadIdx.x;
  int lane = tid & 63;
  int wv   = tid >> 6;
  int lr   = lane & 15;
  int lg   = lane >> 4;
  int r0   = wv * 32;

  const ushort* Ag = reinterpret_cast<const ushort*>(A) + (size_t)(y * BM) * EMBED;
  uint4 a_raw[2][4];
#pragma unroll
  for (int m = 0; m < 2; ++m)
#pragma unroll
    for (int kq = 0; kq < 4; ++kq)
      a_raw[m][kq] = *reinterpret_cast<const uint4*>(
          Ag + (r0 + m * 16 + lr) * EMBED + kq * 32 + lg * 8);

  int cbase = x * 64;
  bool edge = (x == NXT - 1);
  float4 bb[8];
#pragma unroll
  for (int i = 0; i < 8; ++i) {
    int c  = tid + i * 256;
    int e  = c >> 4;
    int v4 = (c & 15) << 2;
    int col = cbase + v4;
    if (!edge) {
      bb[i] = *reinterpret_cast<const float4*>(Bm + (size_t)e * VOCAB + col);
    } else {
      bb[i].x = (col + 0 < VOCAB) ? Bm[(size_t)e * VOCAB + col + 0] : 0.f;
      bb[i].y = (col + 1 < VOCAB) ? Bm[(size_t)e * VOCAB + col + 1] : 0.f;
      bb[i].z = (col + 2 < VOCAB) ? Bm[(size_t)e * VOCAB + col + 2] : 0.f;
      bb[i].w = (col + 3 < VOCAB) ? Bm[(size_t)e * VOCAB + col + 3] : 0.f;
    }
  }
#pragma unroll
  for (int i = 0; i < 8; ++i) {
    int c  = tid + i * 256;
    int e  = c >> 4;
    int v4 = (c & 15) << 2;
    float vals[4] = {bb[i].x, bb[i].y, bb[i].z, bb[i].w};
#pragma unroll
    for (int jj = 0; jj < 4; ++jj) {
      int v   = v4 + jj;
      int off = v * (FLDSP * 2) + ((e * 2) ^ ((v & 28) << 2));
      *reinterpret_cast<ushort*>(BsRaw + off) = f2bf(vals[jj]);
    }
  }
  __syncthreads();

  f32x4 acc[2][4] = {};
#pragma unroll
  for (int kq = 0; kq < 4; ++kq) {
    int ebyte = (kq * 32 + lg * 8) * 2;
    bf16x8 bfr[4];
#pragma unroll
    for (int n = 0; n < 4; ++n) {
      int v   = n * 16 + lr;
      int off = v * (FLDSP * 2) + (ebyte ^ ((v & 28) << 2));
      bfr[n] = *reinterpret_cast<const bf16x8*>(BsRaw + off);
    }
#pragma unroll
    for (int m = 0; m < 2; ++m) {
      bf16x8 af = __builtin_bit_cast(bf16x8, a_raw[m][kq]);
#pragma unroll
      for (int n = 0; n < 4; ++n)
        acc[m][n] = __builtin_amdgcn_mfma_f32_16x16x32_bf16(af, bfr[n], acc[m][n], 0, 0, 0);
    }
  }

  size_t crow0 = (size_t)y * BM + r0;
#pragma unroll
  for (int m = 0; m < 2; ++m) {
#pragma unroll
    for (int n = 0; n < 4; ++n) {
      int colc = cbase + n * 16 + lr;
      if (colc < VOCAB) {
        float* cp = C + (crow0 + m * 16 + lg * 4) * (size_t)VOCAB + colc;
#pragma unroll
        for (int q = 0; q < 4; ++q)
          cp[(size_t)q * VOCAB] = acc[m][n][q];
      }
    }
  }
}

extern "C" void kernel_launch(void* const* d_in, const int* in_sizes, int n_in,
                              void* d_out, int out_size, void* d_ws, size_t ws_size,
                              hipStream_t stream) {
  const int*   idx    = (const int*)d_in[0];
  const float* W_proj = (const float*)d_in[1];
  const float* W_pred = (const float*)d_in[2];
  float*       out    = (float*)d_out;

  __hip_bfloat16* emb = (__hip_bfloat16*)d_ws;                 // [0, 1MB)
  ushort* Btf = (ushort*)((char*)d_ws + (size_t)1048576);      // [1MB, ~13.9MB)
  const size_t needed = (size_t)1048576 + (size_t)VPAD * EMBED * 2;

  embed_bag_kernel<<<BATCH / 4, 256, 0, stream>>>(idx, W_proj, emb);

  if (ws_size >= needed) {
    transpose_b_kernel<<<NXT, 256, 0, stream>>>(W_pred, Btf);
    gemm10_kernel<<<512, 256, 0, stream>>>((const ushort*)emb, Btf, out);
  } else {
    int strips = (NXT + 7) / 8;
    int grid = 8 * strips * 32;
    gemm_kernel<<<grid, 256, 0, stream>>>(emb, W_pred, out);
  }
}

// Round 12
// 372.830 us; speedup vs baseline: 3.8279x; 1.3151x over previous
//
#include <hip/hip_runtime.h>
#include <hip/hip_bf16.h>

#define VOCAB 50257
#define EMBED 128
#define BATCH 4096
#define CTX   8

#define BM 128
#define NXT 786            // 64-col strips
#define VPAD 50304
#define LDSP 136

#define CHUNKS 50          // 1024-col chunks per band (49 full + tail)
#define NBAND 64
#define NTICK (NBAND * CHUNKS)   // 3200

typedef __attribute__((ext_vector_type(8))) short bf16x8;
typedef __attribute__((ext_vector_type(4))) float f32x4;
typedef float f32x4u __attribute__((ext_vector_type(4), aligned(4)));

static __device__ __forceinline__ ushort f2bf(float f) {
  __hip_bfloat16 h = __float2bfloat16(f);
  return *reinterpret_cast<ushort*>(&h);
}

// ---------------- Kernel 1: embedding bag -> bf16 word_emb ----------------
__global__ __launch_bounds__(256) void embed_bag_kernel(
    const int* __restrict__ idx, const float* __restrict__ Wp,
    __hip_bfloat16* __restrict__ emb) {
  int wave = threadIdx.x >> 6;
  int lane = threadIdx.x & 63;
  int row  = blockIdx.x * 4 + wave;
  const int* ri = idx + row * CTX;
  int e0 = lane * 2;
  float s0 = 0.f, s1 = 0.f;
#pragma unroll
  for (int c = 0; c < CTX; ++c) {
    int w = ri[c];
    float2 wv = *reinterpret_cast<const float2*>(Wp + (size_t)w * EMBED + e0);
    s0 += wv.x; s1 += wv.y;
  }
  __hip_bfloat162 pv;
  pv.x = __float2bfloat16(s0);
  pv.y = __float2bfloat16(s1);
  *reinterpret_cast<__hip_bfloat162*>(emb + (size_t)row * EMBED + e0) = pv;
}

// ------- Kernel 1b: W_pred [128][50257]f32 -> Btf fragment-ordered bf16 -------
__global__ __launch_bounds__(256) void transpose_b_kernel(
    const float* __restrict__ Bm, ushort* __restrict__ Btf) {
  __shared__ ushort Bs[64 * LDSP];
  int x = blockIdx.x;
  int cbase = x * 64;
  int tid = threadIdx.x;
  bool edge = (cbase + 64 > VOCAB);
#pragma unroll
  for (int i = 0; i < 8; ++i) {
    int c  = tid + i * 256;
    int e  = c >> 4;
    int v4 = (c & 15) << 2;
    int col = cbase + v4;
    float4 b;
    if (!edge) {
      b = *reinterpret_cast<const float4*>(Bm + (size_t)e * VOCAB + col);
    } else {
      b.x = (col + 0 < VOCAB) ? Bm[(size_t)e * VOCAB + col + 0] : 0.f;
      b.y = (col + 1 < VOCAB) ? Bm[(size_t)e * VOCAB + col + 1] : 0.f;
      b.z = (col + 2 < VOCAB) ? Bm[(size_t)e * VOCAB + col + 2] : 0.f;
      b.w = (col + 3 < VOCAB) ? Bm[(size_t)e * VOCAB + col + 3] : 0.f;
    }
    Bs[(v4 + 0) * LDSP + e] = f2bf(b.x);
    Bs[(v4 + 1) * LDSP + e] = f2bf(b.y);
    Bs[(v4 + 2) * LDSP + e] = f2bf(b.z);
    Bs[(v4 + 3) * LDSP + e] = f2bf(b.w);
  }
  __syncthreads();
  int lane = tid & 63, wv = tid >> 6;
  int lr = lane & 15, lg = lane >> 4;
#pragma unroll
  for (int p = 0; p < 4; ++p) {
    int instr = p * 4 + wv;
    int kq = instr >> 2, n = instr & 3;
    int v  = n * 16 + lr;
    int e0 = kq * 32 + lg * 8;
    uint4 val = *reinterpret_cast<const uint4*>(&Bs[v * LDSP + e0]);
    *reinterpret_cast<uint4*>(Btf + (size_t)x * 8192 + instr * 512 + lane * 8) = val;
  }
}

// ------ Kernel 2: band-ordered tickets + per-wave monotone 1KB row runs ------
// H7 = R9's global write density (band-major atomic tickets -> at any instant
// ~10 consecutive 64-row bands (~129MB < L3) are the chip's entire write
// footprint, so L2/L3 EVICTION order (what DRAM sees) is band-dense) combined
// with R10/R11's amp-1.0 stores (each row piece is a single-writer monotone
// 1KB run staged through a per-wave LDS tile; intra-band seams merge in cache).
// Ticket = (band 64 rows, chunk 1024 cols); block = 4 waves x 16 rows;
// per group (256 cols): 16 n-steps {4 B-frag loads, 4 MFMA swapped, 1
// ds_write_b128} then 16 ds_read + 16 x 1KB single-row stores.
__global__ __launch_bounds__(256, 2) void gemm11_kernel(
    const ushort* __restrict__ A,       // emb bf16 [4096][128]
    const ushort* __restrict__ Btf,     // [786][16][64][8] bf16 frag-ordered
    float* __restrict__ C,
    unsigned int* __restrict__ cnt) {
  __shared__ float Cs[4][64 * 68];      // 69632 B
  __shared__ unsigned int sT;

  int tid  = threadIdx.x;
  int lane = tid & 63;
  int wv   = tid >> 6;
  int lr   = lane & 15;
  int lg   = lane >> 4;

  float* Csw = &Cs[wv][0];
  int wbase = lane * 68;
  int rbas  = (lane & 3) * 16;
  int nofs  = (lane >> 2) * 4;

  for (;;) {
    __syncthreads();
    if (tid == 0) sT = atomicAdd(cnt, 1u);
    __syncthreads();
    unsigned int t = sT;
    if (t >= NTICK) break;

    int band = (int)(t / CHUNKS);
    int c    = (int)(t % CHUNKS);
    int R0   = band * 64 + wv * 16;

    // A fragments for this band's 16 rows (L2-resident, reload per ticket)
    const ushort* Ag = A + (size_t)R0 * EMBED;
    bf16x8 af[4];
#pragma unroll
    for (int kq = 0; kq < 4; ++kq)
      af[kq] = *reinterpret_cast<const bf16x8*>(
          Ag + lr * EMBED + kq * 32 + lg * 8);

    int ngr = (c < CHUNKS - 1) ? 4 : 1;   // chunk 49 = tail group only
    for (int gg = 0; gg < ngr; ++gg) {
      int g = c * 4 + gg;                 // 256-col group id, 0..196
      const ushort* Bg0 = Btf + (size_t)(g * 4) * 8192 + lane * 8;
      if (g != 196) {
#pragma unroll
        for (int ni = 0; ni < 16; ++ni) {
          const ushort* Bp = Bg0 + (size_t)(ni >> 2) * 8192;
          int n = ni & 3;
          bf16x8 b[4];
#pragma unroll
          for (int kq = 0; kq < 4; ++kq)
            b[kq] = *reinterpret_cast<const bf16x8*>(Bp + (kq * 4 + n) * 512);
          f32x4 acc = {0.f, 0.f, 0.f, 0.f};
#pragma unroll
          for (int kq = 0; kq < 4; ++kq)
            acc = __builtin_amdgcn_mfma_f32_16x16x32_bf16(b[kq], af[kq], acc, 0, 0, 0);
          *reinterpret_cast<f32x4*>(&Csw[wbase + ni * 4]) = acc;
        }
        f32x4 v[16];
#pragma unroll
        for (int r = 0; r < 16; ++r)
          v[r] = *reinterpret_cast<const f32x4*>(&Csw[(rbas + r) * 68 + nofs]);
        int colbase = g * 256 + lane * 4;
#pragma unroll
        for (int r = 0; r < 16; ++r)
          *reinterpret_cast<f32x4u*>(C + (size_t)(R0 + r) * VOCAB + colbase) =
              __builtin_bit_cast(f32x4u, v[r]);
      } else {
        // tail: strips 784,785 -> cols 50176..50256 (81 valid)
#pragma unroll
        for (int ni = 0; ni < 8; ++ni) {
          const ushort* Bp = Bg0 + (size_t)(ni >> 2) * 8192;
          int n = ni & 3;
          bf16x8 b[4];
#pragma unroll
          for (int kq = 0; kq < 4; ++kq)
            b[kq] = *reinterpret_cast<const bf16x8*>(Bp + (kq * 4 + n) * 512);
          f32x4 acc = {0.f, 0.f, 0.f, 0.f};
#pragma unroll
          for (int kq = 0; kq < 4; ++kq)
            acc = __builtin_amdgcn_mfma_f32_16x16x32_bf16(b[kq], af[kq], acc, 0, 0, 0);
          *reinterpret_cast<f32x4*>(&Csw[wbase + ni * 4]) = acc;
        }
        int colbase = 196 * 256 + lane * 4;
#pragma unroll
        for (int r = 0; r < 16; ++r) {
          if (lane < 21) {
            f32x4 v = *reinterpret_cast<const f32x4*>(&Csw[(rbas + r) * 68 + nofs]);
            float* cp = C + (size_t)(R0 + r) * VOCAB + colbase;
            if (lane < 20) {
              *reinterpret_cast<f32x4u*>(cp) = __builtin_bit_cast(f32x4u, v);
            } else {
              cp[0] = v[0];               // col 50256
            }
          }
        }
      }
    }
  }
}

// ---------------- Fallback GEMM (R2 style) if ws too small ----------------
#define FLDSP 132
__global__ __launch_bounds__(256, 4) void gemm_kernel(
    const __hip_bfloat16* __restrict__ A,
    const float* __restrict__ Bm,
    float* __restrict__ C) {
  __shared__ char BsRaw[64 * FLDSP * 2];
  int bid = blockIdx.x;
  int k8  = bid & 7;
  int j   = bid >> 3;
  int t   = j >> 5;
  int y   = j & 31;
  int x   = k8 + t * 8;
  if (x >= NXT) return;

  int tid  = threadIdx.x;
  int lane = tid & 63;
  int wv   = tid >> 6;
  int lr   = lane & 15;
  int lg   = lane >> 4;
  int r0   = wv * 32;

  const ushort* Ag = reinterpret_cast<const ushort*>(A) + (size_t)(y * BM) * EMBED;
  uint4 a_raw[2][4];
#pragma unroll
  for (int m = 0; m < 2; ++m)
#pragma unroll
    for (int kq = 0; kq < 4; ++kq)
      a_raw[m][kq] = *reinterpret_cast<const uint4*>(
          Ag + (r0 + m * 16 + lr) * EMBED + kq * 32 + lg * 8);

  int cbase = x * 64;
  bool edge = (x == NXT - 1);
  float4 bb[8];
#pragma unroll
  for (int i = 0; i < 8; ++i) {
    int c  = tid + i * 256;
    int e  = c >> 4;
    int v4 = (c & 15) << 2;
    int col = cbase + v4;
    if (!edge) {
      bb[i] = *reinterpret_cast<const float4*>(Bm + (size_t)e * VOCAB + col);
    } else {
      bb[i].x = (col + 0 < VOCAB) ? Bm[(size_t)e * VOCAB + col + 0] : 0.f;
      bb[i].y = (col + 1 < VOCAB) ? Bm[(size_t)e * VOCAB + col + 1] : 0.f;
      bb[i].z = (col + 2 < VOCAB) ? Bm[(size_t)e * VOCAB + col + 2] : 0.f;
      bb[i].w = (col + 3 < VOCAB) ? Bm[(size_t)e * VOCAB + col + 3] : 0.f;
    }
  }
#pragma unroll
  for (int i = 0; i < 8; ++i) {
    int c  = tid + i * 256;
    int e  = c >> 4;
    int v4 = (c & 15) << 2;
    float vals[4] = {bb[i].x, bb[i].y, bb[i].z, bb[i].w};
#pragma unroll
    for (int jj = 0; jj < 4; ++jj) {
      int v   = v4 + jj;
      int off = v * (FLDSP * 2) + ((e * 2) ^ ((v & 28) << 2));
      *reinterpret_cast<ushort*>(BsRaw + off) = f2bf(vals[jj]);
    }
  }
  __syncthreads();

  f32x4 acc[2][4] = {};
#pragma unroll
  for (int kq = 0; kq < 4; ++kq) {
    int ebyte = (kq * 32 + lg * 8) * 2;
    bf16x8 bfr[4];
#pragma unroll
    for (int n = 0; n < 4; ++n) {
      int v   = n * 16 + lr;
      int off = v * (FLDSP * 2) + (ebyte ^ ((v & 28) << 2));
      bfr[n] = *reinterpret_cast<const bf16x8*>(BsRaw + off);
    }
#pragma unroll
    for (int m = 0; m < 2; ++m) {
      bf16x8 af = __builtin_bit_cast(bf16x8, a_raw[m][kq]);
#pragma unroll
      for (int n = 0; n < 4; ++n)
        acc[m][n] = __builtin_amdgcn_mfma_f32_16x16x32_bf16(af, bfr[n], acc[m][n], 0, 0, 0);
    }
  }

  size_t crow0 = (size_t)y * BM + r0;
#pragma unroll
  for (int m = 0; m < 2; ++m) {
#pragma unroll
    for (int n = 0; n < 4; ++n) {
      int colc = cbase + n * 16 + lr;
      if (colc < VOCAB) {
        float* cp = C + (crow0 + m * 16 + lg * 4) * (size_t)VOCAB + colc;
#pragma unroll
        for (int q = 0; q < 4; ++q)
          cp[(size_t)q * VOCAB] = acc[m][n][q];
      }
    }
  }
}

extern "C" void kernel_launch(void* const* d_in, const int* in_sizes, int n_in,
                              void* d_out, int out_size, void* d_ws, size_t ws_size,
                              hipStream_t stream) {
  const int*   idx    = (const int*)d_in[0];
  const float* W_proj = (const float*)d_in[1];
  const float* W_pred = (const float*)d_in[2];
  float*       out    = (float*)d_out;

  __hip_bfloat16* emb = (__hip_bfloat16*)d_ws;                 // [0, 1MB)
  ushort* Btf = (ushort*)((char*)d_ws + (size_t)1048576);      // [1MB, ~13.9MB)
  unsigned int* cnt = (unsigned int*)((char*)d_ws + (size_t)14680064);  // @14MB
  const size_t needed = (size_t)14680064 + 64;

  embed_bag_kernel<<<BATCH / 4, 256, 0, stream>>>(idx, W_proj, emb);

  if (ws_size >= needed) {
    transpose_b_kernel<<<NXT, 256, 0, stream>>>(W_pred, Btf);
    hipMemsetAsync(cnt, 0, sizeof(unsigned int), stream);
    gemm11_kernel<<<512, 256, 0, stream>>>((const ushort*)emb, Btf, out, cnt);
  } else {
    int strips = (NXT + 7) / 8;
    int grid = 8 * strips * 32;
    gemm_kernel<<<grid, 256, 0, stream>>>(emb, W_pred, out);
  }
}